// Round 7
// baseline (742.608 us; speedup 1.0000x reference)
//
#include <hip/hip_runtime.h>
#include <hip/hip_bf16.h>
#include <stdint.h>

typedef __attribute__((ext_vector_type(8))) short bf16x8;
typedef __attribute__((ext_vector_type(4))) float f32x4;
typedef __attribute__((ext_vector_type(4))) unsigned int u32x4;

#define MFMA __builtin_amdgcn_mfma_f32_16x16x32_bf16

#define BUFSZ 46080          // per double-buffer half: 33KB W2 + 4KB W1 + 8KB W3 (+pad)
#define W1OFF 33792          // 33*1024
#define W3OFF 37888          // W1OFF + 4096
#define SMEM_TOTAL 135680    // 2*BUFSZ + 8*(1024*3 + 2304 + 64)

typedef __attribute__((address_space(3))) unsigned int lds_u32;
typedef const __attribute__((address_space(1))) unsigned int glb_u32;

__device__ __forceinline__ ushort f2bf(float v) {
    __hip_bfloat16 b = __float2bfloat16(v);
    return *reinterpret_cast<ushort*>(&b);
}

// Unit mapping: group g (=degree), main m-th unit: h = g + 63*m (m=0..15);
// extra unit of group g<16: h = 1008+g.
// Register/LDS slot layout: slot 0 = extras chunk (k=g for g<16), slot 1+j = main
// units of groups 2j (k 0..15), 2j+1 (k 16..31).
//
// W2f2 [63 d][33 slot][512]: B-frags, col=lane&15 -> out unit d+63*col, k-slot s per above.
// W2g2 [16 d][9 slot][512]:  B-frags for out unit 1008+d (col 0 only), same slot order.
// W1f  [63 d][2 kc2][2 nt][512]: phase-a B-frags (k=input dim; nt=1 col0 -> 1008+d).
// W3f  [63 d][8 cb][512]: phase-c B-frags (k-slot s -> h2 unit d+63*s; s=16 -> 1008+d).
__global__ void prep_all(const float* __restrict__ W1, const float* __restrict__ W2,
                         const float* __restrict__ W3, const float* __restrict__ b1,
                         const float* __restrict__ b2,
                         ushort* __restrict__ W2f2, ushort* __restrict__ W2g2,
                         ushort* __restrict__ W1f, ushort* __restrict__ W3f,
                         float* __restrict__ b1s2, float* __restrict__ b1e,
                         float* __restrict__ b2s2, float* __restrict__ b2e)
{
    int idx = blockIdx.x * 256 + threadIdx.x;
    if (idx < 63 * 33 * 512) {
        int d = idx / (33 * 512); int rem = idx - d * 33 * 512;
        int slot = rem >> 9, r = rem & 511;
        int lane = r >> 3, e = r & 7;
        int col = lane & 15, s = ((lane >> 4) << 3) + e;
        int hout = d + 63 * col;
        float v = 0.f;
        if (slot == 0) { if (s < 16) v = W2[(size_t)(1008 + s) * 1024 + hout]; }
        else { int j = slot - 1; int g = 2 * j + (s >> 4), m = s & 15;
               if (g <= 62) v = W2[(size_t)(g + 63 * m) * 1024 + hout]; }
        W2f2[idx] = f2bf(v);
    }
    if (idx < 16 * 9 * 512) {
        int d = idx / (9 * 512); int rem = idx - d * 9 * 512;
        int slot = rem >> 9, r = rem & 511;
        int lane = r >> 3, e = r & 7;
        int col = lane & 15, s = ((lane >> 4) << 3) + e;
        float v = 0.f;
        if (col == 0) {
            int hout = 1008 + d;
            if (slot == 0) { if (s < 16) v = W2[(size_t)(1008 + s) * 1024 + hout]; }
            else { int j = slot - 1; int g = 2 * j + (s >> 4), m = s & 15;
                   if (g <= 62) v = W2[(size_t)(g + 63 * m) * 1024 + hout]; }
        }
        W2g2[idx] = f2bf(v);
    }
    if (idx < 63 * 2048) {
        int d = idx >> 11; int rem = idx & 2047;
        int kc2 = rem >> 10, nt = (rem >> 9) & 1, r = rem & 511;
        int lane = r >> 3, e = r & 7;
        int col = lane & 15, k = kc2 * 32 + ((lane >> 4) << 3) + e;
        float v = 0.f;
        if (nt == 0) v = W1[(size_t)k * 1024 + d + 63 * col];
        else if (d < 16 && col == 0) v = W1[(size_t)k * 1024 + 1008 + d];
        W1f[idx] = f2bf(v);
    }
    if (idx < 63 * 8 * 512) {
        int d = idx >> 12; int rem = idx & 4095;
        int cb = rem >> 9, r = rem & 511;
        int lane = r >> 3, e = r & 7;
        int ncol = lane & 15, s = ((lane >> 4) << 3) + e;
        int c = cb * 16 + ncol;
        float v = 0.f;
        if (s < 16) v = W3[(size_t)(d + 63 * s) * 128 + c];
        else if (s == 16 && d < 16) v = W3[(size_t)(1008 + d) * 128 + c];
        W3f[idx] = f2bf(v);
    }
    if (idx < 1008) {
        int d = idx >> 4, m = idx & 15;
        b1s2[idx] = b1[d + 63 * m];
        b2s2[idx] = b2[d + 63 * m];
    }
    if (idx < 16) { b1e[idx] = b1[1008 + idx]; b2e[idx] = b2[1008 + idx]; }
}

// Issue async DMA of step tn's frags into LDS buffer (shared by all 8 waves).
__device__ __forceinline__ void issue_dma(int tn, int w, int lane16, char* buf,
                                          const char* W2p, const char* W2gp,
                                          const char* W1p, const char* W3p)
{
    const int d = tn - 1;
    const int ns = (tn <= 16) ? 9 : (tn <= 28) ? 15 : (tn <= 40) ? 21 : (tn <= 52) ? 27 : 33;
    const int ng = (tn <= 16) ? 9 : 0;
    const char* w2s = W2p + (size_t)d * 33 * 1024;
    const char* w2g = W2gp + (size_t)d * 9 * 1024 - (size_t)ns * 1024;
    const char* w1s = W1p + (size_t)d * 4096 - (size_t)(ns + ng) * 1024;
    const char* w3s = W3p + (size_t)d * 8192 - (size_t)(ns + ng + 4) * 1024;
    const int F = ns + ng + 12;
    for (int f = w; f < F; f += 8) {
        const char* src;
        char* dst;
        if (f < ns)               { src = w2s + f * 1024; dst = buf + f * 1024; }
        else if (f < ns + ng)     { src = w2g + f * 1024; dst = buf + (9 + f - ns) * 1024; }
        else if (f < ns + ng + 4) { src = w1s + f * 1024; dst = buf + W1OFF + (f - ns - ng) * 1024; }
        else                      { src = w3s + f * 1024; dst = buf + W3OFF + (f - ns - ng - 4) * 1024; }
        __builtin_amdgcn_global_load_lds((glb_u32*)(src + lane16), (lds_u32*)dst, 16, 0, 0);
    }
}

// phase b: o = sum over slots of h1f[i] x B[i] from LDS (slot 0 = extras, 1+j = chunk j).
template<int NS, bool T2>
__device__ __forceinline__ void phase_b(const char* __restrict__ w2l,
                                        const bf16x8 (&h1f)[33], int lane16,
                                        f32x4& o1, f32x4& o2)
{
    f32x4 c0 = {0,0,0,0}, c1 = {0,0,0,0}, c2 = {0,0,0,0}, c3 = {0,0,0,0};
    f32x4 g0 = {0,0,0,0}, g1 = {0,0,0,0};
    #pragma unroll
    for (int i = 0; i < NS; ++i) {
        bf16x8 b = *(const bf16x8*)(w2l + i * 1024 + lane16);
        bf16x8 a = h1f[i];
        if ((i & 3) == 0)      c0 = MFMA(a, b, c0, 0, 0, 0);
        else if ((i & 3) == 1) c1 = MFMA(a, b, c1, 0, 0, 0);
        else if ((i & 3) == 2) c2 = MFMA(a, b, c2, 0, 0, 0);
        else                   c3 = MFMA(a, b, c3, 0, 0, 0);
        if constexpr (T2) {
            bf16x8 g = *(const bf16x8*)(w2l + (9 + i) * 1024 + lane16);
            if (i & 1) g1 = MFMA(a, g, g1, 0, 0, 0);
            else       g0 = MFMA(a, g, g0, 0, 0, 0);
        }
    }
    o1 = (c0 + c1) + (c2 + c3);
    if constexpr (T2) o2 = g0 + g1;
}

// 8 waves/WG (128 rows), weights DMA-double-buffered in LDS shared by the WG.
__global__ __launch_bounds__(512, 2)
void maf_main(const float* __restrict__ U, const float* __restrict__ b3,
              const ushort* __restrict__ W2f2, const ushort* __restrict__ W2g2,
              const ushort* __restrict__ W1f, const ushort* __restrict__ W3f,
              const float* __restrict__ b1s2, const float* __restrict__ b1e,
              const float* __restrict__ b2s2, const float* __restrict__ b2e,
              float* __restrict__ out)
{
    extern __shared__ char smem[];
    const int tid = threadIdx.x;
    const int w = tid >> 6, lane = tid & 63;
    const int r16 = lane & 15, q = lane >> 4;
    const int lane16 = lane << 4;
    char*   bufs = smem;                                   // [2][BUFSZ]
    char*   stgm = smem + 92160 + w * 1024;                // chunk-pair transpose staging
    char*   stge = smem + 100352 + w * 1024;               // extras staging (accumulating)
    char*   h2s  = smem + 108544 + w * 1024;               // h2 group staging
    ushort* xbs  = (ushort*)(smem + 116736 + w * 2304);    // [16][72] bf16 x mirror
    float*  lgd  = (float*)(smem + 135168 + w * 64);       // [16] logdet
    const int grow0 = blockIdx.x * 128 + w * 16;

    {
        u32x4 z = {0u, 0u, 0u, 0u};
        *(u32x4*)(stge + lane * 16) = z;
        *(u32x4*)(h2s + lane * 16) = z;
        for (int i = lane; i < 576; i += 64) ((uint32_t*)xbs)[i] = 0u;
        if (lane < 16) lgd[lane] = 0.f;
    }

    bf16x8 h1f[33];
    #pragma unroll
    for (int i = 0; i < 33; ++i) h1f[i] = (bf16x8){0,0,0,0,0,0,0,0};

    f32x4 am0={0,0,0,0},am1={0,0,0,0},am2={0,0,0,0},am3={0,0,0,0};
    f32x4 al0={0,0,0,0},al1={0,0,0,0},al2={0,0,0,0},al3={0,0,0,0};

    for (int t = 0; t < 64; ++t) {
        const int tt = t >> 4, oc = t & 15;
        const int d = t - 1;
        // vector loads BEFORE DMA issue (so their waits don't sit behind DMAs)
        float uu0=0.f, uu1=0.f, uu2=0.f, uu3=0.f;
        if (r16 == oc) {
            const float* up = U + (size_t)(grow0 + q * 4) * 64 + t;
            uu0 = up[0]; uu1 = up[64]; uu2 = up[128]; uu3 = up[192];
        }
        float bb1 = 0.f, bb2 = 0.f, be1 = 0.f, be2 = 0.f;
        if (t > 0) {
            bb1 = b1s2[d * 16 + r16];
            bb2 = b2s2[d * 16 + r16];
            if (d < 16) { be1 = b1e[d]; be2 = b2e[d]; }
        }
        const float b3mu = b3[t], b3ls = b3[64 + t];

        if (t < 63)
            issue_dma(t + 1, w, lane16, bufs + (((t + 1) & 1) * BUFSZ),
                      (const char*)W2f2, (const char*)W2g2,
                      (const char*)W1f, (const char*)W3f);

        const char* buf = bufs + ((t & 1) * BUFSZ);

        if (t > 0) {
            const int jc = d >> 1;

            // ---- phase a (MFMA): finalize h1 group d ----
            {
                const char* w1l = buf + W1OFF;
                bf16x8 xa0 = *(const bf16x8*)(xbs + r16 * 72 + q * 8);
                bf16x8 xa1 = *(const bf16x8*)(xbs + r16 * 72 + 32 + q * 8);
                bf16x8 wf00 = *(const bf16x8*)(w1l + lane16);
                bf16x8 wf10 = *(const bf16x8*)(w1l + 2048 + lane16);
                f32x4 h = {0,0,0,0};
                h = MFMA(xa0, wf00, h, 0, 0, 0);
                h = MFMA(xa1, wf10, h, 0, 0, 0);
                #pragma unroll
                for (int e = 0; e < 4; ++e) {
                    int row = q * 4 + e;
                    ushort hv = f2bf(fmaxf(h[e] + bb1, 0.f));
                    *(ushort*)(stgm + ((row * 64 + ((d & 1) << 5) + r16 * 2) ^ ((row & 3) << 4))) = hv;
                    if (!(d & 1))
                        *(ushort*)(stgm + ((row * 64 + 32 + r16 * 2) ^ ((row & 3) << 4))) = 0;
                }
                if (d < 16) {                                  // extra (17th) unit
                    bf16x8 wf01 = *(const bf16x8*)(w1l + 1024 + lane16);
                    bf16x8 wf11 = *(const bf16x8*)(w1l + 3072 + lane16);
                    f32x4 g = {0,0,0,0};
                    g = MFMA(xa0, wf01, g, 0, 0, 0);
                    g = MFMA(xa1, wf11, g, 0, 0, 0);
                    if (r16 == 0) {
                        #pragma unroll
                        for (int e = 0; e < 4; ++e) {
                            int row = q * 4 + e;
                            *(ushort*)(stge + ((row * 64 + d * 2) ^ ((row & 3) << 4))) =
                                f2bf(fmaxf(g[e] + be1, 0.f));
                        }
                    }
                }
            }
            // read back updated chunk frag(s) into registers
            {
                bf16x8 nf = *(const bf16x8*)(stgm + ((r16 * 64 + q * 16) ^ ((r16 & 3) << 4)));
                switch (jc) {
                    case 0:  h1f[1]=nf;  break; case 1:  h1f[2]=nf;  break;
                    case 2:  h1f[3]=nf;  break; case 3:  h1f[4]=nf;  break;
                    case 4:  h1f[5]=nf;  break; case 5:  h1f[6]=nf;  break;
                    case 6:  h1f[7]=nf;  break; case 7:  h1f[8]=nf;  break;
                    case 8:  h1f[9]=nf;  break; case 9:  h1f[10]=nf; break;
                    case 10: h1f[11]=nf; break; case 11: h1f[12]=nf; break;
                    case 12: h1f[13]=nf; break; case 13: h1f[14]=nf; break;
                    case 14: h1f[15]=nf; break; case 15: h1f[16]=nf; break;
                    case 16: h1f[17]=nf; break; case 17: h1f[18]=nf; break;
                    case 18: h1f[19]=nf; break; case 19: h1f[20]=nf; break;
                    case 20: h1f[21]=nf; break; case 21: h1f[22]=nf; break;
                    case 22: h1f[23]=nf; break; case 23: h1f[24]=nf; break;
                    case 24: h1f[25]=nf; break; case 25: h1f[26]=nf; break;
                    case 26: h1f[27]=nf; break; case 27: h1f[28]=nf; break;
                    case 28: h1f[29]=nf; break; case 29: h1f[30]=nf; break;
                    case 30: h1f[31]=nf; break; default: h1f[32]=nf; break;
                }
                if (d < 16)
                    h1f[0] = *(const bf16x8*)(stge + ((r16 * 64 + q * 16) ^ ((r16 & 3) << 4)));
            }

            // ---- phase b (MFMA, register A-frags, LDS B-frags) ----
            f32x4 o1, o2 = {0,0,0,0};
            if (t <= 16)      phase_b<9,  true >(buf, h1f, lane16, o1, o2);
            else if (t <= 28) phase_b<15, false>(buf, h1f, lane16, o1, o2);
            else if (t <= 40) phase_b<21, false>(buf, h1f, lane16, o1, o2);
            else if (t <= 52) phase_b<27, false>(buf, h1f, lane16, o1, o2);
            else              phase_b<33, false>(buf, h1f, lane16, o1, o2);

            // ---- phase c: h2 transpose staging, then W3 frags read at use ----
            {
                #pragma unroll
                for (int e = 0; e < 4; ++e) {
                    int row = q * 4 + e;
                    ushort hv = f2bf(fmaxf(o1[e] + bb2, 0.f));
                    *(ushort*)(h2s + ((row * 64 + r16 * 2) ^ ((row & 3) << 4))) = hv;
                }
                if (r16 == 0) {
                    #pragma unroll
                    for (int e = 0; e < 4; ++e) {
                        int row = q * 4 + e;
                        ushort hv = (d < 16) ? f2bf(fmaxf(o2[e] + be2, 0.f)) : (ushort)0;
                        *(ushort*)(h2s + ((row * 64 + 32) ^ ((row & 3) << 4))) = hv;
                    }
                }
                bf16x8 ha = *(const bf16x8*)(h2s + ((r16 * 64 + q * 16) ^ ((r16 & 3) << 4)));
                const char* w3l = buf + W3OFF + lane16;
                am0 = MFMA(ha, *(const bf16x8*)(w3l       ), am0, 0, 0, 0);
                am1 = MFMA(ha, *(const bf16x8*)(w3l + 1024), am1, 0, 0, 0);
                am2 = MFMA(ha, *(const bf16x8*)(w3l + 2048), am2, 0, 0, 0);
                am3 = MFMA(ha, *(const bf16x8*)(w3l + 3072), am3, 0, 0, 0);
                al0 = MFMA(ha, *(const bf16x8*)(w3l + 4096), al0, 0, 0, 0);
                al1 = MFMA(ha, *(const bf16x8*)(w3l + 5120), al1, 0, 0, 0);
                al2 = MFMA(ha, *(const bf16x8*)(w3l + 6144), al2, 0, 0, 0);
                al3 = MFMA(ha, *(const bf16x8*)(w3l + 7168), al3, 0, 0, 0);
            }
        }

        // ---- phase d: col t final; owner lanes form x_t ----
        {
            f32x4 vm = (tt == 0) ? am0 : (tt == 1) ? am1 : (tt == 2) ? am2 : am3;
            f32x4 vl = (tt == 0) ? al0 : (tt == 1) ? al1 : (tt == 2) ? al2 : al3;
            if (r16 == oc) {
                float uu[4] = {uu0, uu1, uu2, uu3};
                #pragma unroll
                for (int e = 0; e < 4; ++e) {
                    int row = q * 4 + e;
                    float mu = vm[e] + b3mu;
                    float ls = vl[e] + b3ls;
                    float xv = uu[e] * expf(ls) + mu;
                    out[(size_t)(grow0 + row) * 64 + t] = xv;
                    xbs[row * 72 + t] = f2bf(xv);
                    lgd[row] += ls;
                }
            }
        }

        // one barrier per step: drains this wave's DMAs (vmcnt 0) + makes buffer visible
        __syncthreads();
    }

    if (lane < 16) out[(size_t)32768 * 64 + grow0 + lane] = lgd[lane];
}

extern "C" void kernel_launch(void* const* d_in, const int* in_sizes, int n_in,
                              void* d_out, int out_size, void* d_ws, size_t ws_size,
                              hipStream_t stream) {
    const float* U  = (const float*)d_in[0];
    const float* W1 = (const float*)d_in[1];
    const float* b1 = (const float*)d_in[2];
    const float* W2 = (const float*)d_in[3];
    const float* b2 = (const float*)d_in[4];
    const float* W3 = (const float*)d_in[5];
    const float* b3 = (const float*)d_in[6];
    float* out = (float*)d_out;

    char* ws = (char*)d_ws;
    ushort* W2f2 = (ushort*)ws;                      // 2,128,896 B
    ushort* W2g2 = (ushort*)(ws + 2128896);          //   147,456 B
    ushort* W1f  = (ushort*)(ws + 2276352);          //   258,048 B
    ushort* W3f  = (ushort*)(ws + 2534400);          //   516,096 B
    float*  b1s2 = (float*)(ws + 3050496);           //     4,096 B (1008 used)
    float*  b1e  = (float*)(ws + 3054592);           //       128 B
    float*  b2s2 = (float*)(ws + 3054720);           //     4,032 B
    float*  b2e  = (float*)(ws + 3058752);           //        64 B

    prep_all<<<4160, 256, 0, stream>>>(W1, W2, W3, b1, b2,
                                       W2f2, W2g2, W1f, W3f, b1s2, b1e, b2s2, b2e);

    hipFuncSetAttribute(reinterpret_cast<const void*>(&maf_main),
                        hipFuncAttributeMaxDynamicSharedMemorySize, SMEM_TOTAL);
    maf_main<<<256, 512, SMEM_TOTAL, stream>>>(U, b3, W2f2, W2g2, W1f, W3f,
                                               b1s2, b1e, b2s2, b2e, out);
}

// Round 8
// 330.740 us; speedup vs baseline: 2.2453x; 2.2453x over previous
//
#include <hip/hip_runtime.h>
#include <hip/hip_bf16.h>
#include <stdint.h>

typedef __attribute__((ext_vector_type(8))) short bf16x8;
typedef __attribute__((ext_vector_type(4))) float f32x4;
typedef __attribute__((ext_vector_type(4))) unsigned int u32x4;

#define MFMA __builtin_amdgcn_mfma_f32_16x16x32_bf16

#define BUFSZ 46080          // per double-buffer half: 33KB W2 + 4KB W1 + 8KB W3 (+pad)
#define W1OFF 33792          // 33*1024
#define W3OFF 37888          // W1OFF + 4096
#define SMEM_TOTAL 118272

typedef __attribute__((address_space(3))) unsigned int lds_u32;
typedef const __attribute__((address_space(1))) unsigned int glb_u32;

__device__ __forceinline__ ushort f2bf(float v) {
    __hip_bfloat16 b = __float2bfloat16(v);
    return *reinterpret_cast<ushort*>(&b);
}

// Unit mapping: group g (=degree), main m-th unit: h = g + 63*m (m=0..15);
// extra unit of group g<16: h = 1008+g.
// Slot layout: slot 0 = extras chunk (k=g for g<16), slot 1+j = main units of
// groups 2j (k 0..15), 2j+1 (k 16..31). K-halves: half0 = slots 0..16, half1 = 17..32.
__global__ void prep_all(const float* __restrict__ W1, const float* __restrict__ W2,
                         const float* __restrict__ W3, const float* __restrict__ b1,
                         const float* __restrict__ b2,
                         ushort* __restrict__ W2f2, ushort* __restrict__ W2g2,
                         ushort* __restrict__ W1f, ushort* __restrict__ W3f,
                         float* __restrict__ b1s2, float* __restrict__ b1e,
                         float* __restrict__ b2s2, float* __restrict__ b2e)
{
    int idx = blockIdx.x * 256 + threadIdx.x;
    if (idx < 63 * 33 * 512) {
        int d = idx / (33 * 512); int rem = idx - d * 33 * 512;
        int slot = rem >> 9, r = rem & 511;
        int lane = r >> 3, e = r & 7;
        int col = lane & 15, s = ((lane >> 4) << 3) + e;
        int hout = d + 63 * col;
        float v = 0.f;
        if (slot == 0) { if (s < 16) v = W2[(size_t)(1008 + s) * 1024 + hout]; }
        else { int j = slot - 1; int g = 2 * j + (s >> 4), m = s & 15;
               if (g <= 62) v = W2[(size_t)(g + 63 * m) * 1024 + hout]; }
        W2f2[idx] = f2bf(v);
    }
    if (idx < 16 * 9 * 512) {
        int d = idx / (9 * 512); int rem = idx - d * 9 * 512;
        int slot = rem >> 9, r = rem & 511;
        int lane = r >> 3, e = r & 7;
        int col = lane & 15, s = ((lane >> 4) << 3) + e;
        float v = 0.f;
        if (col == 0) {
            int hout = 1008 + d;
            if (slot == 0) { if (s < 16) v = W2[(size_t)(1008 + s) * 1024 + hout]; }
            else { int j = slot - 1; int g = 2 * j + (s >> 4), m = s & 15;
                   if (g <= 62) v = W2[(size_t)(g + 63 * m) * 1024 + hout]; }
        }
        W2g2[idx] = f2bf(v);
    }
    if (idx < 63 * 2048) {
        int d = idx >> 11; int rem = idx & 2047;
        int kc2 = rem >> 10, nt = (rem >> 9) & 1, r = rem & 511;
        int lane = r >> 3, e = r & 7;
        int col = lane & 15, k = kc2 * 32 + ((lane >> 4) << 3) + e;
        float v = 0.f;
        if (nt == 0) v = W1[(size_t)k * 1024 + d + 63 * col];
        else if (d < 16 && col == 0) v = W1[(size_t)k * 1024 + 1008 + d];
        W1f[idx] = f2bf(v);
    }
    if (idx < 63 * 8 * 512) {
        int d = idx >> 12; int rem = idx & 4095;
        int cb = rem >> 9, r = rem & 511;
        int lane = r >> 3, e = r & 7;
        int ncol = lane & 15, s = ((lane >> 4) << 3) + e;
        int c = cb * 16 + ncol;
        float v = 0.f;
        if (s < 16) v = W3[(size_t)(d + 63 * s) * 128 + c];
        else if (s == 16 && d < 16) v = W3[(size_t)(1008 + d) * 128 + c];
        W3f[idx] = f2bf(v);
    }
    if (idx < 1008) {
        int d = idx >> 4, m = idx & 15;
        b1s2[idx] = b1[d + 63 * m];
        b2s2[idx] = b2[d + 63 * m];
    }
    if (idx < 16) { b1e[idx] = b1[1008 + idx]; b2e[idx] = b2[1008 + idx]; }
}

// Issue async DMA of step tn's frags into LDS buffer (shared by all 8 waves).
__device__ __forceinline__ void issue_dma(int tn, int w, int lane16, char* buf,
                                          const char* W2p, const char* W2gp,
                                          const char* W1p, const char* W3p)
{
    const int d = tn - 1;
    const int ns = (tn <= 16) ? 9 : (tn <= 28) ? 15 : (tn <= 40) ? 21 : (tn <= 52) ? 27 : 33;
    const int ng = (tn <= 16) ? 9 : 0;
    const char* w2s = W2p + (size_t)d * 33 * 1024;
    const char* w2g = W2gp + (size_t)d * 9 * 1024 - (size_t)ns * 1024;
    const char* w1s = W1p + (size_t)d * 4096 - (size_t)(ns + ng) * 1024;
    const char* w3s = W3p + (size_t)d * 8192 - (size_t)(ns + ng + 4) * 1024;
    const int F = ns + ng + 12;
    for (int f = w; f < F; f += 8) {
        const char* src;
        char* dst;
        if (f < ns)               { src = w2s + f * 1024; dst = buf + f * 1024; }
        else if (f < ns + ng)     { src = w2g + f * 1024; dst = buf + (9 + f - ns) * 1024; }
        else if (f < ns + ng + 4) { src = w1s + f * 1024; dst = buf + W1OFF + (f - ns - ng) * 1024; }
        else                      { src = w3s + f * 1024; dst = buf + W3OFF + (f - ns - ng - 4) * 1024; }
        __builtin_amdgcn_global_load_lds((glb_u32*)(src + lane16), (lds_u32*)dst, 16, 0, 0);
    }
}

// phase b partial over this wave's half: slots BASE..BASE+CNT-1, A = h1f[0..CNT).
template<int CNT, int BASE, bool T2>
__device__ __forceinline__ void phase_b(const char* __restrict__ w2l,
                                        const bf16x8 (&h1f)[17], int lane16,
                                        f32x4& o1, f32x4& o2)
{
    f32x4 c0 = {0,0,0,0}, c1 = {0,0,0,0}, c2 = {0,0,0,0}, c3 = {0,0,0,0};
    f32x4 g0 = {0,0,0,0}, g1 = {0,0,0,0};
    #pragma unroll
    for (int i = 0; i < CNT; ++i) {
        bf16x8 b = *(const bf16x8*)(w2l + (BASE + i) * 1024 + lane16);
        bf16x8 a = h1f[i];
        if ((i & 3) == 0)      c0 = MFMA(a, b, c0, 0, 0, 0);
        else if ((i & 3) == 1) c1 = MFMA(a, b, c1, 0, 0, 0);
        else if ((i & 3) == 2) c2 = MFMA(a, b, c2, 0, 0, 0);
        else                   c3 = MFMA(a, b, c3, 0, 0, 0);
        if constexpr (T2) {
            bf16x8 g = *(const bf16x8*)(w2l + (9 + i) * 1024 + lane16);
            if (i & 1) g1 = MFMA(a, g, g1, 0, 0, 0);
            else       g0 = MFMA(a, g, g0, 0, 0, 0);
        }
        if (i == 7) __builtin_amdgcn_sched_barrier(0);   // cap B-frag hoisting
    }
    o1 = (c0 + c1) + (c2 + c3);
    if constexpr (T2) o2 = g0 + g1;
}

// 8 waves/WG: p=w&3 -> 16-row slice, kh=w>>2 -> h1 K-half. 64 rows/WG, grid 512.
__global__ __launch_bounds__(512, 2)
void maf_main(const float* __restrict__ U, const float* __restrict__ b3,
              const ushort* __restrict__ W2f2, const ushort* __restrict__ W2g2,
              const ushort* __restrict__ W1f, const ushort* __restrict__ W3f,
              const float* __restrict__ b1s2, const float* __restrict__ b1e,
              const float* __restrict__ b2s2, const float* __restrict__ b2e,
              float* __restrict__ out)
{
    extern __shared__ char smem[];
    const int tid = threadIdx.x;
    const int w = tid >> 6, lane = tid & 63;
    const int p = w & 3, kh = w >> 2;
    const int r16 = lane & 15, q = lane >> 4;
    const int lane16 = lane << 4;
    char*   bufs  = smem;                                  // [2][BUFSZ] = 92160
    char*   stgm  = smem + 92160 + p * 1024;               // chunk transpose staging
    char*   stge  = smem + 96256 + p * 1024;               // extras staging (accumulating)
    char*   h2s   = smem + 100352 + p * 1024;              // h2 group staging
    char*   pc    = smem + 104448 + p * 1024;              // kh=1 phase-b partial
    ushort* xbs   = (ushort*)(smem + 108544 + p * 2304);   // [16][72] bf16 x mirror
    float*  lscol = (float*)(smem + 117760 + p * 64);      // [16] ls exchange
    float*  lgd   = (float*)(smem + 118016 + p * 64);      // [16] logdet
    const int grow0 = blockIdx.x * 64 + p * 16;

    if (kh == 0) {
        u32x4 z = {0u, 0u, 0u, 0u};
        *(u32x4*)(stge + lane * 16) = z;
        *(u32x4*)(h2s + lane * 16) = z;
        for (int i = lane; i < 576; i += 64) ((uint32_t*)xbs)[i] = 0u;
        if (lane < 16) lgd[lane] = 0.f;
    }
    __syncthreads();

    bf16x8 h1f[17];
    #pragma unroll
    for (int i = 0; i < 17; ++i) h1f[i] = (bf16x8){0,0,0,0,0,0,0,0};

    // kh=0: mu col-tiles (cols 0..63); kh=1: ls col-tiles (cols 64..127)
    f32x4 a0={0,0,0,0}, a1={0,0,0,0}, a2={0,0,0,0}, a3={0,0,0,0};

    for (int t = 0; t < 64; ++t) {
        const int tt = t >> 4, oc = t & 15;
        const int d = t - 1;
        float uu0=0.f, uu1=0.f, uu2=0.f, uu3=0.f;
        if (kh == 0 && r16 == oc) {
            const float* up = U + (size_t)(grow0 + q * 4) * 64 + t;
            uu0 = up[0]; uu1 = up[64]; uu2 = up[128]; uu3 = up[192];
        }
        float bb1 = 0.f, bb2 = 0.f, be1 = 0.f, be2 = 0.f;
        if (t > 0) {
            bb1 = b1s2[d * 16 + r16];
            if (kh == 0) {
                bb2 = b2s2[d * 16 + r16];
                if (d < 16) { be1 = b1e[d]; be2 = b2e[d]; }
            }
        }
        const float b3mu = b3[t], b3ls = b3[64 + t];

        if (t < 63)
            issue_dma(t + 1, w, lane16, bufs + (((t + 1) & 1) * BUFSZ),
                      (const char*)W2f2, (const char*)W2g2,
                      (const char*)W1f, (const char*)W3f);

        const char* buf = bufs + ((t & 1) * BUFSZ);

        if (t > 0) {
            const int s_new = 1 + (d >> 1);
            const int ah = (s_new > 16) ? 1 : 0;   // which half owns the new slot

            // ---- phase a (owner half only): finalize h1 group d ----
            if (kh == ah) {
                const char* w1l = buf + W1OFF;
                bf16x8 xa0 = *(const bf16x8*)(xbs + r16 * 72 + q * 8);
                bf16x8 xa1 = *(const bf16x8*)(xbs + r16 * 72 + 32 + q * 8);
                bf16x8 wf00 = *(const bf16x8*)(w1l + lane16);
                bf16x8 wf10 = *(const bf16x8*)(w1l + 2048 + lane16);
                f32x4 h = {0,0,0,0};
                h = MFMA(xa0, wf00, h, 0, 0, 0);
                h = MFMA(xa1, wf10, h, 0, 0, 0);
                #pragma unroll
                for (int e = 0; e < 4; ++e) {
                    int row = q * 4 + e;
                    ushort hv = f2bf(fmaxf(h[e] + bb1, 0.f));
                    *(ushort*)(stgm + ((row * 64 + ((d & 1) << 5) + r16 * 2) ^ ((row & 3) << 4))) = hv;
                    if (!(d & 1))
                        *(ushort*)(stgm + ((row * 64 + 32 + r16 * 2) ^ ((row & 3) << 4))) = 0;
                }
                if (d < 16) {                                  // extras unit (half0 era)
                    bf16x8 wf01 = *(const bf16x8*)(w1l + 1024 + lane16);
                    bf16x8 wf11 = *(const bf16x8*)(w1l + 3072 + lane16);
                    f32x4 g = {0,0,0,0};
                    g = MFMA(xa0, wf01, g, 0, 0, 0);
                    g = MFMA(xa1, wf11, g, 0, 0, 0);
                    if (r16 == 0) {
                        #pragma unroll
                        for (int e = 0; e < 4; ++e) {
                            int row = q * 4 + e;
                            *(ushort*)(stge + ((row * 64 + d * 2) ^ ((row & 3) << 4))) =
                                f2bf(fmaxf(g[e] + be1, 0.f));
                        }
                    }
                }
                // readback into this wave's local frag index
                const int li = ah ? (s_new - 17) : s_new;
                bf16x8 nf = *(const bf16x8*)(stgm + ((r16 * 64 + q * 16) ^ ((r16 & 3) << 4)));
                switch (li) {
                    case 0:  h1f[0]=nf;  break; case 1:  h1f[1]=nf;  break;
                    case 2:  h1f[2]=nf;  break; case 3:  h1f[3]=nf;  break;
                    case 4:  h1f[4]=nf;  break; case 5:  h1f[5]=nf;  break;
                    case 6:  h1f[6]=nf;  break; case 7:  h1f[7]=nf;  break;
                    case 8:  h1f[8]=nf;  break; case 9:  h1f[9]=nf;  break;
                    case 10: h1f[10]=nf; break; case 11: h1f[11]=nf; break;
                    case 12: h1f[12]=nf; break; case 13: h1f[13]=nf; break;
                    case 14: h1f[14]=nf; break; case 15: h1f[15]=nf; break;
                    default: h1f[16]=nf; break;
                }
                if (d < 16)
                    h1f[0] = *(const bf16x8*)(stge + ((r16 * 64 + q * 16) ^ ((r16 & 3) << 4)));
            }

            // ---- phase b: per-half partial ----
            f32x4 o1 = {0,0,0,0}, o2 = {0,0,0,0};
            if (kh == 0) {
                if (t <= 16)      phase_b<9,  0, true >(buf, h1f, lane16, o1, o2);
                else if (t <= 28) phase_b<15, 0, false>(buf, h1f, lane16, o1, o2);
                else              phase_b<17, 0, false>(buf, h1f, lane16, o1, o2);
            } else if (t >= 33) {
                if (t <= 40)      phase_b<4,  17, false>(buf, h1f, lane16, o1, o2);
                else if (t <= 52) phase_b<10, 17, false>(buf, h1f, lane16, o1, o2);
                else              phase_b<16, 17, false>(buf, h1f, lane16, o1, o2);
            }
            if (t >= 33) {
                if (kh == 1) *(f32x4*)(pc + lane * 16) = o1;
                __syncthreads();                                        // B1
                if (kh == 0) o1 += *(const f32x4*)(pc + lane * 16);
            }

            // ---- h2 formation + transpose staging (kh=0 only) ----
            if (kh == 0) {
                #pragma unroll
                for (int e = 0; e < 4; ++e) {
                    int row = q * 4 + e;
                    ushort hv = f2bf(fmaxf(o1[e] + bb2, 0.f));
                    *(ushort*)(h2s + ((row * 64 + r16 * 2) ^ ((row & 3) << 4))) = hv;
                }
                if (r16 == 0) {
                    #pragma unroll
                    for (int e = 0; e < 4; ++e) {
                        int row = q * 4 + e;
                        ushort hv = (d < 16) ? f2bf(fmaxf(o2[e] + be2, 0.f)) : (ushort)0;
                        *(ushort*)(h2s + ((row * 64 + 32) ^ ((row & 3) << 4))) = hv;
                    }
                }
            }
            __syncthreads();                                            // B2

            // ---- phase c: kh=0 -> mu tiles (cb 0..3), kh=1 -> ls tiles (cb 4..7) ----
            {
                bf16x8 ha = *(const bf16x8*)(h2s + ((r16 * 64 + q * 16) ^ ((r16 & 3) << 4)));
                const char* w3l = buf + W3OFF + kh * 4096 + lane16;
                a0 = MFMA(ha, *(const bf16x8*)(w3l       ), a0, 0, 0, 0);
                a1 = MFMA(ha, *(const bf16x8*)(w3l + 1024), a1, 0, 0, 0);
                a2 = MFMA(ha, *(const bf16x8*)(w3l + 2048), a2, 0, 0, 0);
                a3 = MFMA(ha, *(const bf16x8*)(w3l + 3072), a3, 0, 0, 0);
            }
        }

        // ---- phase d: kh=1 publishes ls col t; kh=0 forms x_t ----
        {
            f32x4 v = (tt == 0) ? a0 : (tt == 1) ? a1 : (tt == 2) ? a2 : a3;
            if (kh == 1 && r16 == oc) {
                f32x4 lsv;
                #pragma unroll
                for (int e = 0; e < 4; ++e) {
                    float ls = v[e] + b3ls;
                    lsv[e] = ls;
                    lgd[q * 4 + e] += ls;
                }
                *(f32x4*)(lscol + q * 4) = lsv;
            }
            __syncthreads();                                            // B3
            if (kh == 0 && r16 == oc) {
                f32x4 lsv = *(const f32x4*)(lscol + q * 4);
                float uu[4] = {uu0, uu1, uu2, uu3};
                #pragma unroll
                for (int e = 0; e < 4; ++e) {
                    int row = q * 4 + e;
                    float mu = v[e] + b3mu;
                    float xv = uu[e] * expf(lsv[e]) + mu;
                    out[(size_t)(grow0 + row) * 64 + t] = xv;
                    xbs[row * 72 + t] = f2bf(xv);
                }
            }
        }
        __syncthreads();                                                // B4 (DMA drain + xbs)
    }

    if (kh == 1 && lane < 16) out[(size_t)32768 * 64 + grow0 + lane] = lgd[lane];
}

extern "C" void kernel_launch(void* const* d_in, const int* in_sizes, int n_in,
                              void* d_out, int out_size, void* d_ws, size_t ws_size,
                              hipStream_t stream) {
    const float* U  = (const float*)d_in[0];
    const float* W1 = (const float*)d_in[1];
    const float* b1 = (const float*)d_in[2];
    const float* W2 = (const float*)d_in[3];
    const float* b2 = (const float*)d_in[4];
    const float* W3 = (const float*)d_in[5];
    const float* b3 = (const float*)d_in[6];
    float* out = (float*)d_out;

    char* ws = (char*)d_ws;
    ushort* W2f2 = (ushort*)ws;                      // 2,128,896 B
    ushort* W2g2 = (ushort*)(ws + 2128896);          //   147,456 B
    ushort* W1f  = (ushort*)(ws + 2276352);          //   258,048 B
    ushort* W3f  = (ushort*)(ws + 2534400);          //   516,096 B
    float*  b1s2 = (float*)(ws + 3050496);           //     4,096 B (1008 used)
    float*  b1e  = (float*)(ws + 3054592);           //       128 B
    float*  b2s2 = (float*)(ws + 3054720);           //     4,032 B
    float*  b2e  = (float*)(ws + 3058752);           //        64 B

    prep_all<<<4160, 256, 0, stream>>>(W1, W2, W3, b1, b2,
                                       W2f2, W2g2, W1f, W3f, b1s2, b1e, b2s2, b2e);

    hipFuncSetAttribute(reinterpret_cast<const void*>(&maf_main),
                        hipFuncAttributeMaxDynamicSharedMemorySize, SMEM_TOTAL);
    maf_main<<<512, 512, SMEM_TOTAL, stream>>>(U, b3, W2f2, W2g2, W1f, W3f,
                                               b1s2, b1e, b2s2, b2e, out);
}